// Round 7
// baseline (160.229 us; speedup 1.0000x reference)
//
#include <hip/hip_runtime.h>
#include <stdint.h>

typedef __attribute__((ext_vector_type(4))) float f32x4;
typedef __attribute__((ext_vector_type(8))) short bf16x8;
typedef __attribute__((ext_vector_type(4))) unsigned short u16x4;

#define AS1(p) ((const __attribute__((address_space(1))) void*)(p))
#define AS3(p) ((__attribute__((address_space(3))) void*)(p))

__device__ __forceinline__ unsigned short f2bf(float f){
  unsigned u = __builtin_bit_cast(unsigned, f);
  u += 0x7FFF + ((u >> 16) & 1);     // round-to-nearest-even
  return (unsigned short)(u >> 16);
}

// ---------- cast f32 -> bf16, 4 elems/thread ----------
__global__ __launch_bounds__(256) void k_cast(const float* __restrict__ in,
                                              unsigned short* __restrict__ out, int n4){
  int i = blockIdx.x*256 + threadIdx.x;
  if (i >= n4) return;
  f32x4 v = ((const f32x4*)in)[i];
  u16x4 o;
  o.x = f2bf(v.x); o.y = f2bf(v.y); o.z = f2bf(v.z); o.w = f2bf(v.w);
  ((u16x4*)out)[i] = o;
}

// ---------- transpose + cast: in f32 [R][C] -> out bf16 [C][R] ----------
__global__ __launch_bounds__(256) void k_transpose_cast(const float* __restrict__ in,
                                                        unsigned short* __restrict__ out,
                                                        int R, int C){
  __shared__ float tile[32][33];
  int tx = threadIdx.x & 31, ty = threadIdx.x >> 5;       // 32 x 8
  int c0 = blockIdx.x*32, r0 = blockIdx.y*32;
  #pragma unroll
  for (int i = 0; i < 4; i++)
    tile[ty + i*8][tx] = in[(size_t)(r0 + ty + i*8)*C + c0 + tx];
  __syncthreads();
  #pragma unroll
  for (int i = 0; i < 4; i++)
    out[(size_t)(c0 + ty + i*8)*R + r0 + tx] = f2bf(tile[tx][ty + i*8]);
}

// ---------- bf16 GEMM:  out[M][N] = act(A[M][K] @ Bt[N][K]^T + bias) ----------
// 128x128 tile, 4 waves (2x2), each wave 64x64 via 4x4 of 16x16x32 MFMA.
template<bool RELU, bool OUTBF16>
__global__ __launch_bounds__(256) void k_gemm(const unsigned short* __restrict__ A,
                                              const unsigned short* __restrict__ Bt,
                                              const float* __restrict__ bias,
                                              void* __restrict__ out, int K, int N){
  __shared__ short As[128*32];
  __shared__ short Bs[128*32];
  const int tid  = threadIdx.x;
  const int lane = tid & 63, wid = tid >> 6;
  const int wr = wid >> 1, wc = wid & 1;
  const int l15 = lane & 15, lk = lane >> 4;
  const int bm = blockIdx.x, bn = blockIdx.y;

  // staging: thread -> (row = tid/4 [+64], k-elem = (tid%4)*8), 16B each
  const unsigned short* Ab = A  + (size_t)bm*128*K + (size_t)(tid >> 2)*K + (tid & 3)*8;
  const unsigned short* Bb = Bt + (size_t)bn*128*K + (size_t)(tid >> 2)*K + (tid & 3)*8;
  short* AsD = &As[tid*8];
  short* BsD = &Bs[tid*8];

  f32x4 acc[4][4];
  #pragma unroll
  for (int i = 0; i < 4; i++)
    #pragma unroll
    for (int j = 0; j < 4; j++) acc[i][j] = (f32x4){0.f,0.f,0.f,0.f};

  for (int k0 = 0; k0 < K; k0 += 32){
    __builtin_amdgcn_global_load_lds(AS1(Ab + k0),        AS3(AsD),        16, 0, 0);
    __builtin_amdgcn_global_load_lds(AS1(Ab + 64*K + k0), AS3(AsD + 2048), 16, 0, 0);
    __builtin_amdgcn_global_load_lds(AS1(Bb + k0),        AS3(BsD),        16, 0, 0);
    __builtin_amdgcn_global_load_lds(AS1(Bb + 64*K + k0), AS3(BsD + 2048), 16, 0, 0);
    __syncthreads();

    bf16x8 af[4], bg[4];
    #pragma unroll
    for (int i = 0; i < 4; i++)
      af[i] = *(const bf16x8*)&As[(wr*64 + i*16 + l15)*32 + lk*8];
    #pragma unroll
    for (int j = 0; j < 4; j++)
      bg[j] = *(const bf16x8*)&Bs[(wc*64 + j*16 + l15)*32 + lk*8];
    #pragma unroll
    for (int i = 0; i < 4; i++)
      #pragma unroll
      for (int j = 0; j < 4; j++)
        acc[i][j] = __builtin_amdgcn_mfma_f32_16x16x32_bf16(af[i], bg[j], acc[i][j], 0, 0, 0);
    __syncthreads();
  }

  // epilogue: C/D layout col = lane&15, row = (lane>>4)*4 + r
  const int row0 = bm*128 + wr*64 + lk*4;
  const int col0 = bn*128 + wc*64 + l15;
  #pragma unroll
  for (int i = 0; i < 4; i++){
    #pragma unroll
    for (int j = 0; j < 4; j++){
      int col = col0 + j*16;
      float b = bias[col];
      #pragma unroll
      for (int r = 0; r < 4; r++){
        int row = row0 + i*16 + r;
        float v = acc[i][j][r] + b;
        if (RELU) v = fmaxf(v, 0.f);
        if (OUTBF16) ((unsigned short*)out)[(size_t)row*N + col] = f2bf(v);
        else         ((float*)out)[(size_t)row*N + col] = v;
      }
    }
  }
}

// ================= KNN via uniform grid (counting sort + shell search) ======
#define GD 14
#define GD3 (GD*GD*GD)          // 2744 cells, ~3 pts/cell
#define NL 8192

__device__ __forceinline__ int cellcoord(float x){
  int c = (int)(x * (float)GD);
  return min(GD-1, max(0, c));
}

// zero the 4096-int hist (hipMemsetAsync's fillBufferAligned cost 39 us/replay!)
__global__ __launch_bounds__(64) void k_zero(int* __restrict__ p){
  ((int4*)p)[threadIdx.x*16 + 0] = (int4){0,0,0,0};
  #pragma unroll
  for (int i = 1; i < 16; i++)
    ((int4*)p)[threadIdx.x*16 + i] = (int4){0,0,0,0};
}

__global__ __launch_bounds__(256) void k_hist(const float* __restrict__ l_pos,
                                              int* __restrict__ hist){
  int i = blockIdx.x*256 + threadIdx.x;       // exactly 8192 threads
  float x = l_pos[3*i], y = l_pos[3*i+1], z = l_pos[3*i+2];
  int c = (cellcoord(z)*GD + cellcoord(y))*GD + cellcoord(x);
  atomicAdd(&hist[c], 1);
}

// exclusive prefix over 4096 (padded) hist entries -> cellStart + cursor copy
__global__ __launch_bounds__(1024) void k_scan(const int* __restrict__ hist,
                                               int* __restrict__ cellStart,
                                               int* __restrict__ cursor){
  __shared__ int s[1024];
  int t = threadIdx.x;
  int4 v = ((const int4*)hist)[t];
  int sum = v.x + v.y + v.z + v.w;
  s[t] = sum;
  __syncthreads();
  for (int off = 1; off < 1024; off <<= 1){
    int val = (t >= off) ? s[t-off] : 0;
    __syncthreads();
    s[t] += val;
    __syncthreads();
  }
  int base = s[t] - sum;                     // exclusive prefix of thread sums
  int4 cs;
  cs.x = base;
  cs.y = base + v.x;
  cs.z = base + v.x + v.y;
  cs.w = base + v.x + v.y + v.z;
  ((int4*)cellStart)[t] = cs;
  ((int4*)cursor)[t]    = cs;
}

__global__ __launch_bounds__(256) void k_scatter(const float* __restrict__ l_pos,
                                                 int* __restrict__ cursor,
                                                 float4* __restrict__ sorted){
  int i = blockIdx.x*256 + threadIdx.x;       // exactly 8192 threads
  float x = l_pos[3*i], y = l_pos[3*i+1], z = l_pos[3*i+2];
  int c = (cellcoord(z)*GD + cellcoord(y))*GD + cellcoord(x);
  int slot = atomicAdd(&cursor[c], 1);
  float4 q; q.x = x; q.y = y; q.z = z; q.w = __int_as_float(i);
  sorted[slot] = q;
}

// Dedup-safe + (d, index)-lexicographic insert: order-independent top-3
// (deterministic despite atomic scatter order; matches top_k's lower-index
// tie rule) and idempotent under re-insertion of already-held elements
// (needed for the repeated lane merges).
#define KNN_INS(dv, gi) \
  if (gi != i0 && gi != i1 && gi != i2 && \
      (dv < d2 || (dv == d2 && gi < i2))){ \
    if (dv < d1 || (dv == d1 && gi < i1)){ \
      d2 = d1; i2 = i1; \
      if (dv < d0 || (dv == d0 && gi < i0)){ d1 = d0; i1 = i0; d0 = dv; i0 = gi; } \
      else { d1 = dv; i1 = gi; } \
    } else { d2 = dv; i2 = gi; } \
  }

#define KNN_MERGE8() \
  _Pragma("unroll") \
  for (int m = 1; m < 8; m <<= 1){ \
    float e0 = __shfl_xor(d0, m), e1 = __shfl_xor(d1, m), e2 = __shfl_xor(d2, m); \
    int   j0 = __shfl_xor(i0, m), j1 = __shfl_xor(i1, m), j2 = __shfl_xor(i2, m); \
    KNN_INS(e0, j0); KNN_INS(e1, j1); KNN_INS(e2, j2); \
  }

// 8 lanes cooperate per h-point: 262144 threads = 4096 waves = 16 waves/CU
__global__ __launch_bounds__(256) void k_knn_grid(const float* __restrict__ h_pos,
                                                  const int* __restrict__ cellStart,
                                                  const float4* __restrict__ sorted,
                                                  float* __restrict__ w,
                                                  int* __restrict__ idx){
  const int t = blockIdx.x*256 + threadIdx.x;
  const int h = t >> 3, sl = t & 7;
  const float hx = h_pos[3*h], hy = h_pos[3*h+1], hz = h_pos[3*h+2];
  const int cx = cellcoord(hx), cy = cellcoord(hy), cz = cellcoord(hz);
  const float cs = 1.0f/(float)GD;
  float d0 = 3e38f, d1 = 3e38f, d2 = 3e38f;
  int   i0 = 0x7fffffff, i1 = 0x7fffffff, i2 = 0x7fffffff;

  // ring 0+1: 27 cells, lane-strided across the 8-lane group
  for (int ci = sl; ci < 27; ci += 8){
    int dz = ci/9 - 1, dy = (ci - (ci/9)*9)/3 - 1, dx = ci % 3 - 1;
    int zz = cz+dz, yy = cy+dy, xx = cx+dx;
    if ((unsigned)zz >= GD || (unsigned)yy >= GD || (unsigned)xx >= GD) continue;
    int c = (zz*GD + yy)*GD + xx;
    int p0 = cellStart[c], p1 = cellStart[c+1];
    for (int p = p0; p < p1; p++){
      float4 qq = sorted[p];
      float ddx = hx - qq.x, ddy = hy - qq.y, ddz = hz - qq.z;
      float d = fmaf(ddx, ddx, fmaf(ddy, ddy, ddz*ddz));
      int gi = __float_as_int(qq.w);
      KNN_INS(d, gi);
    }
  }
  KNN_MERGE8();

  // rare fallback: expand shells until top-3 provably inside scanned box
  for (int r = 2; r < GD; r++){
    int rp = r - 1;
    float B = 3e38f;
    if (cx - rp > 0)      B = fminf(B, hx - (float)(cx-rp)*cs);
    if (cx + rp + 1 < GD) B = fminf(B, (float)(cx+rp+1)*cs - hx);
    if (cy - rp > 0)      B = fminf(B, hy - (float)(cy-rp)*cs);
    if (cy + rp + 1 < GD) B = fminf(B, (float)(cy+rp+1)*cs - hy);
    if (cz - rp > 0)      B = fminf(B, hz - (float)(cz-rp)*cs);
    if (cz + rp + 1 < GD) B = fminf(B, (float)(cz+rp+1)*cs - hz);
    if (d2 <= B*B) break;                     // group-uniform after merge

    int side = 2*r + 1, ss = side*side, tot = ss*side;
    for (int ci = sl; ci < tot; ci += 8){
      int dz = ci/ss - r;
      int rem = ci - (ci/ss)*ss;
      int dy = rem/side - r, dx = rem - (rem/side)*side - r;
      int adx = abs(dx), ady = abs(dy), adz = abs(dz);
      if (max(adx, max(ady, adz)) < r) continue;   // shell-exact: skip interior
      int zz = cz+dz, yy = cy+dy, xx = cx+dx;
      if ((unsigned)zz >= GD || (unsigned)yy >= GD || (unsigned)xx >= GD) continue;
      int c = (zz*GD + yy)*GD + xx;
      int p0 = cellStart[c], p1 = cellStart[c+1];
      for (int p = p0; p < p1; p++){
        float4 qq = sorted[p];
        float ddx = hx - qq.x, ddy = hy - qq.y, ddz = hz - qq.z;
        float d = fmaf(ddx, ddx, fmaf(ddy, ddy, ddz*ddz));
        int gi = __float_as_int(qq.w);
        KNN_INS(d, gi);
      }
    }
    KNN_MERGE8();
  }

  if (sl == 0){
    w[3*h+0] = 1.0f/fmaxf(d0, 1e-16f); idx[3*h+0] = i0;
    w[3*h+1] = 1.0f/fmaxf(d1, 1e-16f); idx[3*h+1] = i1;
    w[3*h+2] = 1.0f/fmaxf(d2, 1e-16f); idx[3*h+2] = i2;
  }
}

// ---------- KNN gather: l_y rows, weighted avg, add into out ----------
__global__ __launch_bounds__(256) void k_knn_gather(const float* __restrict__ w,
                                                    const int* __restrict__ idx,
                                                    const float* __restrict__ l_y,
                                                    float* __restrict__ out){
  const int t = blockIdx.x*256 + threadIdx.x;
  const int h = t >> 5, lane = t & 31;               // 32 lanes x float4 = 128 feats
  const float w0 = w[h*3+0], w1 = w[h*3+1], w2 = w[h*3+2];
  const int   j0 = idx[h*3+0], j1 = idx[h*3+1], j2 = idx[h*3+2];
  const f32x4* ly4 = (const f32x4*)l_y;
  f32x4 a = ly4[(size_t)j0*32 + lane]*w0
          + ly4[(size_t)j1*32 + lane]*w1
          + ly4[(size_t)j2*32 + lane]*w2;
  float inv = 1.0f/(w0 + w1 + w2);
  f32x4* o4 = (f32x4*)out;
  size_t oi = (size_t)h*32 + lane;
  o4[oi] = o4[oi] + a*inv;
}

extern "C" void kernel_launch(void* const* d_in, const int* in_sizes, int n_in,
                              void* d_out, int out_size, void* d_ws, size_t ws_size,
                              hipStream_t stream){
  const float* emb   = (const float*)d_in[0];
  const float* l_y   = (const float*)d_in[1];
  const float* l_pos = (const float*)d_in[2];
  const float* h_pos = (const float*)d_in[3];
  const float* W1    = (const float*)d_in[4];
  const float* b1    = (const float*)d_in[5];
  const float* W2    = (const float*)d_in[6];
  const float* b2    = (const float*)d_in[7];
  const float* W3    = (const float*)d_in[8];
  const float* b3    = (const float*)d_in[9];

  const int M = 32768, H = 512, O = 128;

  char* ws = (char*)d_ws;
  unsigned short* bufA = (unsigned short*)(ws);                  // 32 MB: emb_bf16, later X2
  unsigned short* bufB = (unsigned short*)(ws + 33554432);       // 32 MB: X1
  unsigned short* W1t  = (unsigned short*)(ws + 67108864);       // 512 KB
  unsigned short* W2t  = (unsigned short*)(ws + 67633152);       // 512 KB
  unsigned short* W3t  = (unsigned short*)(ws + 68157440);       // 128 KB
  int*    hist      = (int*)   (ws + 68288512);                  // 16 KB (4096 padded)
  int*    cellStart = (int*)   (ws + 68304896);                  // 16 KB
  int*    cursor    = (int*)   (ws + 68321280);                  // 16 KB
  float4* sorted    = (float4*)(ws + 68354048);                  // 128 KB
  float* wts = (float*)(ws + 74579968);                          // 384 KB
  int*   idx = (int*)  (ws + 74973184);                          // 384 KB

  // casts / transposes
  k_cast<<<dim3(M*H/4/256), 256, 0, stream>>>(emb, bufA, M*H/4);
  k_transpose_cast<<<dim3(H/32, H/32), 256, 0, stream>>>(W1, W1t, H, H);
  k_transpose_cast<<<dim3(H/32, H/32), 256, 0, stream>>>(W2, W2t, H, H);
  k_transpose_cast<<<dim3(O/32, H/32), 256, 0, stream>>>(W3, W3t, H, O);

  // MLP
  k_gemm<true,  true ><<<dim3(M/128, H/128), 256, 0, stream>>>(bufA, W1t, b1, bufB, H, H);
  k_gemm<true,  true ><<<dim3(M/128, H/128), 256, 0, stream>>>(bufB, W2t, b2, bufA, H, H);
  k_gemm<false, false><<<dim3(M/128, O/128), 256, 0, stream>>>(bufA, W3t, b3, d_out, H, O);

  // KNN interpolate via uniform grid (+= into out)
  k_zero<<<dim3(1), 64, 0, stream>>>(hist);
  k_hist<<<dim3(NL/256), 256, 0, stream>>>(l_pos, hist);
  k_scan<<<dim3(1), 1024, 0, stream>>>(hist, cellStart, cursor);
  k_scatter<<<dim3(NL/256), 256, 0, stream>>>(l_pos, cursor, sorted);
  k_knn_grid<<<dim3(M*8/256), 256, 0, stream>>>(h_pos, cellStart, sorted, wts, idx);
  k_knn_gather<<<dim3(M*32/256), 256, 0, stream>>>(wts, idx, l_y, (float*)d_out);
}

// Round 8
// 153.607 us; speedup vs baseline: 1.0431x; 1.0431x over previous
//
#include <hip/hip_runtime.h>
#include <stdint.h>

typedef __attribute__((ext_vector_type(4))) float f32x4;
typedef __attribute__((ext_vector_type(8))) short bf16x8;
typedef __attribute__((ext_vector_type(4))) unsigned short u16x4;

#define AS1(p) ((const __attribute__((address_space(1))) void*)(p))
#define AS3(p) ((__attribute__((address_space(3))) void*)(p))

__device__ __forceinline__ unsigned short f2bf(float f){
  unsigned u = __builtin_bit_cast(unsigned, f);
  u += 0x7FFF + ((u >> 16) & 1);     // round-to-nearest-even
  return (unsigned short)(u >> 16);
}

// ---------- transpose + cast: in f32 [R][C] -> out bf16 [C][R] ----------
__global__ __launch_bounds__(256) void k_transpose_cast(const float* __restrict__ in,
                                                        unsigned short* __restrict__ out,
                                                        int R, int C){
  __shared__ float tile[32][33];
  int tx = threadIdx.x & 31, ty = threadIdx.x >> 5;       // 32 x 8
  int c0 = blockIdx.x*32, r0 = blockIdx.y*32;
  #pragma unroll
  for (int i = 0; i < 4; i++)
    tile[ty + i*8][tx] = in[(size_t)(r0 + ty + i*8)*C + c0 + tx];
  __syncthreads();
  #pragma unroll
  for (int i = 0; i < 4; i++)
    out[(size_t)(c0 + ty + i*8)*R + r0 + tx] = f2bf(tile[tx][ty + i*8]);
}

// ---------- bf16 GEMM:  out[M][N] = act(A[M][K] @ Bt[N][K]^T + bias) ----------
// 128x128 tile, 4 waves (2x2), each wave 64x64 via 4x4 of 16x16x32 MFMA.
// AF32: A is f32 in global; cast to bf16 during reg-staging (fuses k_cast).
template<bool AF32, bool RELU, bool OUTBF16>
__global__ __launch_bounds__(256) void k_gemm(const void* __restrict__ Av,
                                              const unsigned short* __restrict__ Bt,
                                              const float* __restrict__ bias,
                                              void* __restrict__ out, int K, int N){
  __shared__ short As[128*32];
  __shared__ short Bs[128*32];
  const int tid  = threadIdx.x;
  const int lane = tid & 63, wid = tid >> 6;
  const int wr = wid >> 1, wc = wid & 1;
  const int l15 = lane & 15, lk = lane >> 4;
  const int bm = blockIdx.x, bn = blockIdx.y;

  // staging: thread -> (row = tid/4 [+64], k-elem = (tid%4)*8), 16B bf16 each
  const unsigned short* Ab16 = (const unsigned short*)Av
                             + (size_t)bm*128*K + (size_t)(tid >> 2)*K + (tid & 3)*8;
  const float*          Ab32 = (const float*)Av
                             + (size_t)bm*128*K + (size_t)(tid >> 2)*K + (tid & 3)*8;
  const unsigned short* Bb = Bt + (size_t)bn*128*K + (size_t)(tid >> 2)*K + (tid & 3)*8;
  short* AsD = &As[tid*8];
  short* BsD = &Bs[tid*8];

  f32x4 acc[4][4];
  #pragma unroll
  for (int i = 0; i < 4; i++)
    #pragma unroll
    for (int j = 0; j < 4; j++) acc[i][j] = (f32x4){0.f,0.f,0.f,0.f};

  for (int k0 = 0; k0 < K; k0 += 32){
    if constexpr (AF32){
      f32x4 a0 = *(const f32x4*)(Ab32 + k0);
      f32x4 a1 = *(const f32x4*)(Ab32 + k0 + 4);
      f32x4 a2 = *(const f32x4*)(Ab32 + (size_t)64*K + k0);
      f32x4 a3 = *(const f32x4*)(Ab32 + (size_t)64*K + k0 + 4);
      bf16x8 p0, p1;
      #pragma unroll
      for (int j = 0; j < 4; j++){
        p0[j]   = (short)f2bf(a0[j]);
        p0[j+4] = (short)f2bf(a1[j]);
        p1[j]   = (short)f2bf(a2[j]);
        p1[j+4] = (short)f2bf(a3[j]);
      }
      *(bf16x8*)AsD          = p0;
      *(bf16x8*)(AsD + 2048) = p1;
    } else {
      __builtin_amdgcn_global_load_lds(AS1(Ab16 + k0),                  AS3(AsD),        16, 0, 0);
      __builtin_amdgcn_global_load_lds(AS1(Ab16 + (size_t)64*K + k0),   AS3(AsD + 2048), 16, 0, 0);
    }
    __builtin_amdgcn_global_load_lds(AS1(Bb + k0),                 AS3(BsD),        16, 0, 0);
    __builtin_amdgcn_global_load_lds(AS1(Bb + (size_t)64*K + k0),  AS3(BsD + 2048), 16, 0, 0);
    __syncthreads();

    bf16x8 af[4], bg[4];
    #pragma unroll
    for (int i = 0; i < 4; i++)
      af[i] = *(const bf16x8*)&As[(wr*64 + i*16 + l15)*32 + lk*8];
    #pragma unroll
    for (int j = 0; j < 4; j++)
      bg[j] = *(const bf16x8*)&Bs[(wc*64 + j*16 + l15)*32 + lk*8];
    #pragma unroll
    for (int i = 0; i < 4; i++)
      #pragma unroll
      for (int j = 0; j < 4; j++)
        acc[i][j] = __builtin_amdgcn_mfma_f32_16x16x32_bf16(af[i], bg[j], acc[i][j], 0, 0, 0);
    __syncthreads();
  }

  // epilogue: C/D layout col = lane&15, row = (lane>>4)*4 + r
  const int row0 = bm*128 + wr*64 + lk*4;
  const int col0 = bn*128 + wc*64 + l15;
  #pragma unroll
  for (int i = 0; i < 4; i++){
    #pragma unroll
    for (int j = 0; j < 4; j++){
      int col = col0 + j*16;
      float b = bias[col];
      #pragma unroll
      for (int r = 0; r < 4; r++){
        int row = row0 + i*16 + r;
        float v = acc[i][j][r] + b;
        if (RELU) v = fmaxf(v, 0.f);
        if (OUTBF16) ((unsigned short*)out)[(size_t)row*N + col] = f2bf(v);
        else         ((float*)out)[(size_t)row*N + col] = v;
      }
    }
  }
}

// ================= KNN via uniform grid (counting sort + shell search) ======
#define GD 14
#define GD3 (GD*GD*GD)          // 2744 cells, ~3 pts/cell
#define NL 8192

__device__ __forceinline__ int cellcoord(float x){
  int c = (int)(x * (float)GD);
  return min(GD-1, max(0, c));
}

// zero the 4096-int hist (in-graph custom zero; rocclr fill kernel is noisy)
__global__ __launch_bounds__(64) void k_zero(int* __restrict__ p){
  #pragma unroll
  for (int i = 0; i < 16; i++)
    ((int4*)p)[threadIdx.x*16 + i] = (int4){0,0,0,0};
}

__global__ __launch_bounds__(256) void k_hist(const float* __restrict__ l_pos,
                                              int* __restrict__ hist){
  int i = blockIdx.x*256 + threadIdx.x;       // exactly 8192 threads
  float x = l_pos[3*i], y = l_pos[3*i+1], z = l_pos[3*i+2];
  int c = (cellcoord(z)*GD + cellcoord(y))*GD + cellcoord(x);
  atomicAdd(&hist[c], 1);
}

// exclusive prefix over 4096 (padded) hist entries -> cellStart + cursor copy
__global__ __launch_bounds__(1024) void k_scan(const int* __restrict__ hist,
                                               int* __restrict__ cellStart,
                                               int* __restrict__ cursor){
  __shared__ int s[1024];
  int t = threadIdx.x;
  int4 v = ((const int4*)hist)[t];
  int sum = v.x + v.y + v.z + v.w;
  s[t] = sum;
  __syncthreads();
  for (int off = 1; off < 1024; off <<= 1){
    int val = (t >= off) ? s[t-off] : 0;
    __syncthreads();
    s[t] += val;
    __syncthreads();
  }
  int base = s[t] - sum;                     // exclusive prefix of thread sums
  int4 cs;
  cs.x = base;
  cs.y = base + v.x;
  cs.z = base + v.x + v.y;
  cs.w = base + v.x + v.y + v.z;
  ((int4*)cellStart)[t] = cs;
  ((int4*)cursor)[t]    = cs;
}

__global__ __launch_bounds__(256) void k_scatter(const float* __restrict__ l_pos,
                                                 int* __restrict__ cursor,
                                                 float4* __restrict__ sorted){
  int i = blockIdx.x*256 + threadIdx.x;       // exactly 8192 threads
  float x = l_pos[3*i], y = l_pos[3*i+1], z = l_pos[3*i+2];
  int c = (cellcoord(z)*GD + cellcoord(y))*GD + cellcoord(x);
  int slot = atomicAdd(&cursor[c], 1);
  float4 q; q.x = x; q.y = y; q.z = z; q.w = __int_as_float(i);
  sorted[slot] = q;
}

// Dedup-safe + (d, index)-lexicographic insert: order-independent top-3
// (deterministic despite atomic scatter order; matches top_k's lower-index
// tie rule) and idempotent under re-insertion (needed for lane merges).
#define KNN_INS(dv, gi) \
  if (gi != i0 && gi != i1 && gi != i2 && \
      (dv < d2 || (dv == d2 && gi < i2))){ \
    if (dv < d1 || (dv == d1 && gi < i1)){ \
      d2 = d1; i2 = i1; \
      if (dv < d0 || (dv == d0 && gi < i0)){ d1 = d0; i1 = i0; d0 = dv; i0 = gi; } \
      else { d1 = dv; i1 = gi; } \
    } else { d2 = dv; i2 = gi; } \
  }

#define KNN_MERGE16() \
  _Pragma("unroll") \
  for (int m = 1; m < 16; m <<= 1){ \
    float e0 = __shfl_xor(d0, m), e1 = __shfl_xor(d1, m), e2 = __shfl_xor(d2, m); \
    int   j0 = __shfl_xor(i0, m), j1 = __shfl_xor(i1, m), j2 = __shfl_xor(i2, m); \
    KNN_INS(e0, j0); KNN_INS(e1, j1); KNN_INS(e2, j2); \
  }

// 16 lanes cooperate per h-point: 524288 threads = 8192 waves = 32 waves/CU;
// each lane's serial chain is ~2 cells (vs 4 at 8 lanes).
__global__ __launch_bounds__(256) void k_knn_grid(const float* __restrict__ h_pos,
                                                  const int* __restrict__ cellStart,
                                                  const float4* __restrict__ sorted,
                                                  float* __restrict__ w,
                                                  int* __restrict__ idx){
  const int t = blockIdx.x*256 + threadIdx.x;
  const int h = t >> 4, sl = t & 15;
  const float hx = h_pos[3*h], hy = h_pos[3*h+1], hz = h_pos[3*h+2];
  const int cx = cellcoord(hx), cy = cellcoord(hy), cz = cellcoord(hz);
  const float cs = 1.0f/(float)GD;
  float d0 = 3e38f, d1 = 3e38f, d2 = 3e38f;
  int   i0 = 0x7fffffff, i1 = 0x7fffffff, i2 = 0x7fffffff;

  // ring 0+1: 27 cells, lane-strided across the 16-lane group
  for (int ci = sl; ci < 27; ci += 16){
    int dz = ci/9 - 1, dy = (ci - (ci/9)*9)/3 - 1, dx = ci % 3 - 1;
    int zz = cz+dz, yy = cy+dy, xx = cx+dx;
    if ((unsigned)zz >= GD || (unsigned)yy >= GD || (unsigned)xx >= GD) continue;
    int c = (zz*GD + yy)*GD + xx;
    int p0 = cellStart[c], p1 = cellStart[c+1];
    for (int p = p0; p < p1; p++){
      float4 qq = sorted[p];
      float ddx = hx - qq.x, ddy = hy - qq.y, ddz = hz - qq.z;
      float d = fmaf(ddx, ddx, fmaf(ddy, ddy, ddz*ddz));
      int gi = __float_as_int(qq.w);
      KNN_INS(d, gi);
    }
  }
  KNN_MERGE16();

  // rare fallback: expand shells until top-3 provably inside scanned box
  for (int r = 2; r < GD; r++){
    int rp = r - 1;
    float B = 3e38f;
    if (cx - rp > 0)      B = fminf(B, hx - (float)(cx-rp)*cs);
    if (cx + rp + 1 < GD) B = fminf(B, (float)(cx+rp+1)*cs - hx);
    if (cy - rp > 0)      B = fminf(B, hy - (float)(cy-rp)*cs);
    if (cy + rp + 1 < GD) B = fminf(B, (float)(cy+rp+1)*cs - hy);
    if (cz - rp > 0)      B = fminf(B, hz - (float)(cz-rp)*cs);
    if (cz + rp + 1 < GD) B = fminf(B, (float)(cz+rp+1)*cs - hz);
    if (d2 <= B*B) break;                     // group-uniform after merge

    int side = 2*r + 1, ss = side*side, tot = ss*side;
    for (int ci = sl; ci < tot; ci += 16){
      int dz = ci/ss - r;
      int rem = ci - (ci/ss)*ss;
      int dy = rem/side - r, dx = rem - (rem/side)*side - r;
      int adx = abs(dx), ady = abs(dy), adz = abs(dz);
      if (max(adx, max(ady, adz)) < r) continue;   // shell-exact: skip interior
      int zz = cz+dz, yy = cy+dy, xx = cx+dx;
      if ((unsigned)zz >= GD || (unsigned)yy >= GD || (unsigned)xx >= GD) continue;
      int c = (zz*GD + yy)*GD + xx;
      int p0 = cellStart[c], p1 = cellStart[c+1];
      for (int p = p0; p < p1; p++){
        float4 qq = sorted[p];
        float ddx = hx - qq.x, ddy = hy - qq.y, ddz = hz - qq.z;
        float d = fmaf(ddx, ddx, fmaf(ddy, ddy, ddz*ddz));
        int gi = __float_as_int(qq.w);
        KNN_INS(d, gi);
      }
    }
    KNN_MERGE16();
  }

  if (sl == 0){
    w[3*h+0] = 1.0f/fmaxf(d0, 1e-16f); idx[3*h+0] = i0;
    w[3*h+1] = 1.0f/fmaxf(d1, 1e-16f); idx[3*h+1] = i1;
    w[3*h+2] = 1.0f/fmaxf(d2, 1e-16f); idx[3*h+2] = i2;
  }
}

// ---------- KNN gather: l_y rows, weighted avg, add into out ----------
__global__ __launch_bounds__(256) void k_knn_gather(const float* __restrict__ w,
                                                    const int* __restrict__ idx,
                                                    const float* __restrict__ l_y,
                                                    float* __restrict__ out){
  const int t = blockIdx.x*256 + threadIdx.x;
  const int h = t >> 5, lane = t & 31;               // 32 lanes x float4 = 128 feats
  const float w0 = w[h*3+0], w1 = w[h*3+1], w2 = w[h*3+2];
  const int   j0 = idx[h*3+0], j1 = idx[h*3+1], j2 = idx[h*3+2];
  const f32x4* ly4 = (const f32x4*)l_y;
  f32x4 a = ly4[(size_t)j0*32 + lane]*w0
          + ly4[(size_t)j1*32 + lane]*w1
          + ly4[(size_t)j2*32 + lane]*w2;
  float inv = 1.0f/(w0 + w1 + w2);
  f32x4* o4 = (f32x4*)out;
  size_t oi = (size_t)h*32 + lane;
  o4[oi] = o4[oi] + a*inv;
}

extern "C" void kernel_launch(void* const* d_in, const int* in_sizes, int n_in,
                              void* d_out, int out_size, void* d_ws, size_t ws_size,
                              hipStream_t stream){
  const float* emb   = (const float*)d_in[0];
  const float* l_y   = (const float*)d_in[1];
  const float* l_pos = (const float*)d_in[2];
  const float* h_pos = (const float*)d_in[3];
  const float* W1    = (const float*)d_in[4];
  const float* b1    = (const float*)d_in[5];
  const float* W2    = (const float*)d_in[6];
  const float* b2    = (const float*)d_in[7];
  const float* W3    = (const float*)d_in[8];
  const float* b3    = (const float*)d_in[9];

  const int M = 32768, H = 512, O = 128;

  char* ws = (char*)d_ws;
  unsigned short* bufA = (unsigned short*)(ws);                  // 32 MB: X2
  unsigned short* bufB = (unsigned short*)(ws + 33554432);       // 32 MB: X1
  unsigned short* W1t  = (unsigned short*)(ws + 67108864);       // 512 KB
  unsigned short* W2t  = (unsigned short*)(ws + 67633152);       // 512 KB
  unsigned short* W3t  = (unsigned short*)(ws + 68157440);       // 128 KB
  int*    hist      = (int*)   (ws + 68288512);                  // 16 KB (4096 padded)
  int*    cellStart = (int*)   (ws + 68304896);                  // 16 KB
  int*    cursor    = (int*)   (ws + 68321280);                  // 16 KB
  float4* sorted    = (float4*)(ws + 68354048);                  // 128 KB
  float* wts = (float*)(ws + 74579968);                          // 384 KB
  int*   idx = (int*)  (ws + 74973184);                          // 384 KB

  // weight transposes (bf16 [N][K] for MFMA B-operand)
  k_transpose_cast<<<dim3(H/32, H/32), 256, 0, stream>>>(W1, W1t, H, H);
  k_transpose_cast<<<dim3(H/32, H/32), 256, 0, stream>>>(W2, W2t, H, H);
  k_transpose_cast<<<dim3(O/32, H/32), 256, 0, stream>>>(W3, W3t, H, O);

  // MLP (GEMM1 reads f32 emb directly, cast fused into staging)
  k_gemm<true,  true,  true ><<<dim3(M/128, H/128), 256, 0, stream>>>(emb,  W1t, b1, bufB, H, H);
  k_gemm<false, true,  true ><<<dim3(M/128, H/128), 256, 0, stream>>>(bufB, W2t, b2, bufA, H, H);
  k_gemm<false, false, false><<<dim3(M/128, O/128), 256, 0, stream>>>(bufA, W3t, b3, d_out, H, O);

  // KNN interpolate via uniform grid (+= into out)
  k_zero<<<dim3(1), 64, 0, stream>>>(hist);
  k_hist<<<dim3(NL/256), 256, 0, stream>>>(l_pos, hist);
  k_scan<<<dim3(1), 1024, 0, stream>>>(hist, cellStart, cursor);
  k_scatter<<<dim3(NL/256), 256, 0, stream>>>(l_pos, cursor, sorted);
  k_knn_grid<<<dim3(M*16/256), 256, 0, stream>>>(h_pos, cellStart, sorted, wts, idx);
  k_knn_gather<<<dim3(M*32/256), 256, 0, stream>>>(wts, idx, l_y, (float*)d_out);
}

// Round 9
// 147.515 us; speedup vs baseline: 1.0862x; 1.0413x over previous
//
#include <hip/hip_runtime.h>
#include <stdint.h>

typedef __attribute__((ext_vector_type(4))) float f32x4;
typedef __attribute__((ext_vector_type(8))) short bf16x8;
typedef __attribute__((ext_vector_type(4))) unsigned short u16x4;

#define AS1(p) ((const __attribute__((address_space(1))) void*)(p))
#define AS3(p) ((__attribute__((address_space(3))) void*)(p))

__device__ __forceinline__ unsigned short f2bf(float f){
  unsigned u = __builtin_bit_cast(unsigned, f);
  u += 0x7FFF + ((u >> 16) & 1);     // round-to-nearest-even
  return (unsigned short)(u >> 16);
}

// ---------- transpose + cast: in f32 [R][C] -> out bf16 [C][R] ----------
__global__ __launch_bounds__(256) void k_transpose_cast(const float* __restrict__ in,
                                                        unsigned short* __restrict__ out,
                                                        int R, int C){
  __shared__ float tile[32][33];
  int tx = threadIdx.x & 31, ty = threadIdx.x >> 5;       // 32 x 8
  int c0 = blockIdx.x*32, r0 = blockIdx.y*32;
  #pragma unroll
  for (int i = 0; i < 4; i++)
    tile[ty + i*8][tx] = in[(size_t)(r0 + ty + i*8)*C + c0 + tx];
  __syncthreads();
  #pragma unroll
  for (int i = 0; i < 4; i++)
    out[(size_t)(c0 + ty + i*8)*R + r0 + tx] = f2bf(tile[tx][ty + i*8]);
}

// ---------- bf16 GEMM:  out[M][N] = act(A[M][K] @ Bt[N][K]^T + bias) ----------
// 128x128 tile, 4 waves (2x2), 16x16x32 MFMA, double-buffered LDS (2-phase:
// STAGE(t+1) issued before compute(t) so the barrier drain overlaps MFMA),
// 16B-chunk XOR swizzle (c^=(row>>1)&3) applied at stage-source AND read
// (dest linear for global_load_lds) to kill the 8-way ds_read conflict.
// AF32: A is f32; cast fused into reg-staging (T14: load early, write late).
template<bool AF32, bool RELU, bool OUTBF16>
__global__ __launch_bounds__(256) void k_gemm(const void* __restrict__ Av,
                                              const unsigned short* __restrict__ Bt,
                                              const float* __restrict__ bias,
                                              void* __restrict__ out, int K, int N){
  __shared__ short As[2][128*32];
  __shared__ short Bs[2][128*32];
  const int tid  = threadIdx.x;
  const int lane = tid & 63, wid = tid >> 6;
  const int wr = wid >> 1, wc = wid & 1;
  const int l15 = lane & 15, lk = lane >> 4;
  const int bm = blockIdx.x, bn = blockIdx.y;

  // staging geometry: thread -> (row = tid>>2 [+64], chunk c = tid&3), 16B.
  // source chunk is the inverse-swizzle so linear dest == swizzled layout.
  const int srow = tid >> 2;
  const int slk  = (tid & 3) ^ ((srow >> 1) & 3);
  const unsigned short* Ab16 = (const unsigned short*)Av
                             + (size_t)bm*128*K + (size_t)srow*K + slk*8;
  const float*          Ab32 = (const float*)Av
                             + (size_t)bm*128*K + (size_t)srow*K + slk*8;
  const unsigned short* Bb = Bt + (size_t)bn*128*K + (size_t)srow*K + slk*8;

  f32x4 acc[4][4];
  #pragma unroll
  for (int i = 0; i < 4; i++)
    #pragma unroll
    for (int j = 0; j < 4; j++) acc[i][j] = (f32x4){0.f,0.f,0.f,0.f};

  const int nt = K >> 5;
  int cur = 0;

  // ---- prologue: stage tile 0 ----
  f32x4 a0, a1, a2, a3;
  if constexpr (AF32){
    a0 = *(const f32x4*)(Ab32);
    a1 = *(const f32x4*)(Ab32 + 4);
    a2 = *(const f32x4*)(Ab32 + (size_t)64*K);
    a3 = *(const f32x4*)(Ab32 + (size_t)64*K + 4);
  } else {
    __builtin_amdgcn_global_load_lds(AS1(Ab16),                AS3(&As[0][tid*8]),        16, 0, 0);
    __builtin_amdgcn_global_load_lds(AS1(Ab16 + (size_t)64*K), AS3(&As[0][tid*8 + 2048]), 16, 0, 0);
  }
  __builtin_amdgcn_global_load_lds(AS1(Bb),                AS3(&Bs[0][tid*8]),        16, 0, 0);
  __builtin_amdgcn_global_load_lds(AS1(Bb + (size_t)64*K), AS3(&Bs[0][tid*8 + 2048]), 16, 0, 0);
  if constexpr (AF32){
    bf16x8 p0, p1;
    #pragma unroll
    for (int j = 0; j < 4; j++){
      p0[j]   = (short)f2bf(a0[j]);  p0[j+4] = (short)f2bf(a1[j]);
      p1[j]   = (short)f2bf(a2[j]);  p1[j+4] = (short)f2bf(a3[j]);
    }
    *(bf16x8*)&As[0][tid*8]        = p0;
    *(bf16x8*)&As[0][tid*8 + 2048] = p1;
  }
  __syncthreads();

  for (int t = 0; t < nt; t++){
    const bool pf = (t + 1 < nt);
    const int k1 = (t + 1) << 5;
    // ---- issue next tile's loads (fly during compute below) ----
    if (pf){
      if constexpr (AF32){
        a0 = *(const f32x4*)(Ab32 + k1);
        a1 = *(const f32x4*)(Ab32 + k1 + 4);
        a2 = *(const f32x4*)(Ab32 + (size_t)64*K + k1);
        a3 = *(const f32x4*)(Ab32 + (size_t)64*K + k1 + 4);
      } else {
        __builtin_amdgcn_global_load_lds(AS1(Ab16 + k1),                AS3(&As[cur^1][tid*8]),        16, 0, 0);
        __builtin_amdgcn_global_load_lds(AS1(Ab16 + (size_t)64*K + k1), AS3(&As[cur^1][tid*8 + 2048]), 16, 0, 0);
      }
      __builtin_amdgcn_global_load_lds(AS1(Bb + k1),                AS3(&Bs[cur^1][tid*8]),        16, 0, 0);
      __builtin_amdgcn_global_load_lds(AS1(Bb + (size_t)64*K + k1), AS3(&Bs[cur^1][tid*8 + 2048]), 16, 0, 0);
    }

    // ---- compute tile t (swizzled reads: 2-way max, conflict-free) ----
    bf16x8 af[4], bg[4];
    #pragma unroll
    for (int i = 0; i < 4; i++){
      int R = wr*64 + i*16 + l15;
      af[i] = *(const bf16x8*)&As[cur][R*32 + (lk ^ ((R >> 1) & 3))*8];
    }
    #pragma unroll
    for (int j = 0; j < 4; j++){
      int R = wc*64 + j*16 + l15;
      bg[j] = *(const bf16x8*)&Bs[cur][R*32 + (lk ^ ((R >> 1) & 3))*8];
    }
    #pragma unroll
    for (int i = 0; i < 4; i++)
      #pragma unroll
      for (int j = 0; j < 4; j++)
        acc[i][j] = __builtin_amdgcn_mfma_f32_16x16x32_bf16(af[i], bg[j], acc[i][j], 0, 0, 0);

    __syncthreads();   // loads for t+1 had the whole compute phase to fly

    if constexpr (AF32){
      if (pf){
        bf16x8 p0, p1;
        #pragma unroll
        for (int j = 0; j < 4; j++){
          p0[j]   = (short)f2bf(a0[j]);  p0[j+4] = (short)f2bf(a1[j]);
          p1[j]   = (short)f2bf(a2[j]);  p1[j+4] = (short)f2bf(a3[j]);
        }
        *(bf16x8*)&As[cur^1][tid*8]        = p0;
        *(bf16x8*)&As[cur^1][tid*8 + 2048] = p1;
        __syncthreads();
      }
    }
    cur ^= 1;
  }

  // epilogue: C/D layout col = lane&15, row = (lane>>4)*4 + r
  const int row0 = bm*128 + wr*64 + lk*4;
  const int col0 = bn*128 + wc*64 + l15;
  #pragma unroll
  for (int i = 0; i < 4; i++){
    #pragma unroll
    for (int j = 0; j < 4; j++){
      int col = col0 + j*16;
      float b = bias[col];
      #pragma unroll
      for (int r = 0; r < 4; r++){
        int row = row0 + i*16 + r;
        float v = acc[i][j][r] + b;
        if (RELU) v = fmaxf(v, 0.f);
        if (OUTBF16) ((unsigned short*)out)[(size_t)row*N + col] = f2bf(v);
        else         ((float*)out)[(size_t)row*N + col] = v;
      }
    }
  }
}

// ================= KNN via uniform grid (counting sort + shell search) ======
#define GD 14
#define GD3 (GD*GD*GD)          // 2744 cells, ~3 pts/cell
#define NL 8192

__device__ __forceinline__ int cellcoord(float x){
  int c = (int)(x * (float)GD);
  return min(GD-1, max(0, c));
}

// zero the 4096-int hist (in-graph custom zero; rocclr fill kernel is noisy)
__global__ __launch_bounds__(64) void k_zero(int* __restrict__ p){
  #pragma unroll
  for (int i = 0; i < 16; i++)
    ((int4*)p)[threadIdx.x*16 + i] = (int4){0,0,0,0};
}

__global__ __launch_bounds__(256) void k_hist(const float* __restrict__ l_pos,
                                              int* __restrict__ hist){
  int i = blockIdx.x*256 + threadIdx.x;       // exactly 8192 threads
  float x = l_pos[3*i], y = l_pos[3*i+1], z = l_pos[3*i+2];
  int c = (cellcoord(z)*GD + cellcoord(y))*GD + cellcoord(x);
  atomicAdd(&hist[c], 1);
}

// exclusive prefix over 4096 (padded) hist entries -> cellStart + cursor copy
__global__ __launch_bounds__(1024) void k_scan(const int* __restrict__ hist,
                                               int* __restrict__ cellStart,
                                               int* __restrict__ cursor){
  __shared__ int s[1024];
  int t = threadIdx.x;
  int4 v = ((const int4*)hist)[t];
  int sum = v.x + v.y + v.z + v.w;
  s[t] = sum;
  __syncthreads();
  for (int off = 1; off < 1024; off <<= 1){
    int val = (t >= off) ? s[t-off] : 0;
    __syncthreads();
    s[t] += val;
    __syncthreads();
  }
  int base = s[t] - sum;                     // exclusive prefix of thread sums
  int4 cs;
  cs.x = base;
  cs.y = base + v.x;
  cs.z = base + v.x + v.y;
  cs.w = base + v.x + v.y + v.z;
  ((int4*)cellStart)[t] = cs;
  ((int4*)cursor)[t]    = cs;
}

__global__ __launch_bounds__(256) void k_scatter(const float* __restrict__ l_pos,
                                                 int* __restrict__ cursor,
                                                 float4* __restrict__ sorted){
  int i = blockIdx.x*256 + threadIdx.x;       // exactly 8192 threads
  float x = l_pos[3*i], y = l_pos[3*i+1], z = l_pos[3*i+2];
  int c = (cellcoord(z)*GD + cellcoord(y))*GD + cellcoord(x);
  int slot = atomicAdd(&cursor[c], 1);
  float4 q; q.x = x; q.y = y; q.z = z; q.w = __int_as_float(i);
  sorted[slot] = q;
}

// Dedup-safe + (d, index)-lexicographic insert: order-independent top-3
// (deterministic despite atomic scatter order; matches top_k's lower-index
// tie rule) and idempotent under re-insertion (needed for lane merges).
#define KNN_INS(dv, gi) \
  if (gi != i0 && gi != i1 && gi != i2 && \
      (dv < d2 || (dv == d2 && gi < i2))){ \
    if (dv < d1 || (dv == d1 && gi < i1)){ \
      d2 = d1; i2 = i1; \
      if (dv < d0 || (dv == d0 && gi < i0)){ d1 = d0; i1 = i0; d0 = dv; i0 = gi; } \
      else { d1 = dv; i1 = gi; } \
    } else { d2 = dv; i2 = gi; } \
  }

#define KNN_MERGE16() \
  _Pragma("unroll") \
  for (int m = 1; m < 16; m <<= 1){ \
    float e0 = __shfl_xor(d0, m), e1 = __shfl_xor(d1, m), e2 = __shfl_xor(d2, m); \
    int   j0 = __shfl_xor(i0, m), j1 = __shfl_xor(i1, m), j2 = __shfl_xor(i2, m); \
    KNN_INS(e0, j0); KNN_INS(e1, j1); KNN_INS(e2, j2); \
  }

// 16 lanes cooperate per h-point: 524288 threads = 8192 waves = 32 waves/CU
__global__ __launch_bounds__(256) void k_knn_grid(const float* __restrict__ h_pos,
                                                  const int* __restrict__ cellStart,
                                                  const float4* __restrict__ sorted,
                                                  float* __restrict__ w,
                                                  int* __restrict__ idx){
  const int t = blockIdx.x*256 + threadIdx.x;
  const int h = t >> 4, sl = t & 15;
  const float hx = h_pos[3*h], hy = h_pos[3*h+1], hz = h_pos[3*h+2];
  const int cx = cellcoord(hx), cy = cellcoord(hy), cz = cellcoord(hz);
  const float cs = 1.0f/(float)GD;
  float d0 = 3e38f, d1 = 3e38f, d2 = 3e38f;
  int   i0 = 0x7fffffff, i1 = 0x7fffffff, i2 = 0x7fffffff;

  // ring 0+1: 27 cells, lane-strided across the 16-lane group
  for (int ci = sl; ci < 27; ci += 16){
    int dz = ci/9 - 1, dy = (ci - (ci/9)*9)/3 - 1, dx = ci % 3 - 1;
    int zz = cz+dz, yy = cy+dy, xx = cx+dx;
    if ((unsigned)zz >= GD || (unsigned)yy >= GD || (unsigned)xx >= GD) continue;
    int c = (zz*GD + yy)*GD + xx;
    int p0 = cellStart[c], p1 = cellStart[c+1];
    for (int p = p0; p < p1; p++){
      float4 qq = sorted[p];
      float ddx = hx - qq.x, ddy = hy - qq.y, ddz = hz - qq.z;
      float d = fmaf(ddx, ddx, fmaf(ddy, ddy, ddz*ddz));
      int gi = __float_as_int(qq.w);
      KNN_INS(d, gi);
    }
  }
  KNN_MERGE16();

  // rare fallback: expand shells until top-3 provably inside scanned box
  for (int r = 2; r < GD; r++){
    int rp = r - 1;
    float B = 3e38f;
    if (cx - rp > 0)      B = fminf(B, hx - (float)(cx-rp)*cs);
    if (cx + rp + 1 < GD) B = fminf(B, (float)(cx+rp+1)*cs - hx);
    if (cy - rp > 0)      B = fminf(B, hy - (float)(cy-rp)*cs);
    if (cy + rp + 1 < GD) B = fminf(B, (float)(cy+rp+1)*cs - hy);
    if (cz - rp > 0)      B = fminf(B, hz - (float)(cz-rp)*cs);
    if (cz + rp + 1 < GD) B = fminf(B, (float)(cz+rp+1)*cs - hz);
    if (d2 <= B*B) break;                     // group-uniform after merge

    int side = 2*r + 1, ss = side*side, tot = ss*side;
    for (int ci = sl; ci < tot; ci += 16){
      int dz = ci/ss - r;
      int rem = ci - (ci/ss)*ss;
      int dy = rem/side - r, dx = rem - (rem/side)*side - r;
      int adx = abs(dx), ady = abs(dy), adz = abs(dz);
      if (max(adx, max(ady, adz)) < r) continue;   // shell-exact: skip interior
      int zz = cz+dz, yy = cy+dy, xx = cx+dx;
      if ((unsigned)zz >= GD || (unsigned)yy >= GD || (unsigned)xx >= GD) continue;
      int c = (zz*GD + yy)*GD + xx;
      int p0 = cellStart[c], p1 = cellStart[c+1];
      for (int p = p0; p < p1; p++){
        float4 qq = sorted[p];
        float ddx = hx - qq.x, ddy = hy - qq.y, ddz = hz - qq.z;
        float d = fmaf(ddx, ddx, fmaf(ddy, ddy, ddz*ddz));
        int gi = __float_as_int(qq.w);
        KNN_INS(d, gi);
      }
    }
    KNN_MERGE16();
  }

  if (sl == 0){
    w[3*h+0] = 1.0f/fmaxf(d0, 1e-16f); idx[3*h+0] = i0;
    w[3*h+1] = 1.0f/fmaxf(d1, 1e-16f); idx[3*h+1] = i1;
    w[3*h+2] = 1.0f/fmaxf(d2, 1e-16f); idx[3*h+2] = i2;
  }
}

// ---------- KNN gather: l_y rows, weighted avg, add into out ----------
__global__ __launch_bounds__(256) void k_knn_gather(const float* __restrict__ w,
                                                    const int* __restrict__ idx,
                                                    const float* __restrict__ l_y,
                                                    float* __restrict__ out){
  const int t = blockIdx.x*256 + threadIdx.x;
  const int h = t >> 5, lane = t & 31;               // 32 lanes x float4 = 128 feats
  const float w0 = w[h*3+0], w1 = w[h*3+1], w2 = w[h*3+2];
  const int   j0 = idx[h*3+0], j1 = idx[h*3+1], j2 = idx[h*3+2];
  const f32x4* ly4 = (const f32x4*)l_y;
  f32x4 a = ly4[(size_t)j0*32 + lane]*w0
          + ly4[(size_t)j1*32 + lane]*w1
          + ly4[(size_t)j2*32 + lane]*w2;
  float inv = 1.0f/(w0 + w1 + w2);
  f32x4* o4 = (f32x4*)out;
  size_t oi = (size_t)h*32 + lane;
  o4[oi] = o4[oi] + a*inv;
}

extern "C" void kernel_launch(void* const* d_in, const int* in_sizes, int n_in,
                              void* d_out, int out_size, void* d_ws, size_t ws_size,
                              hipStream_t stream){
  const float* emb   = (const float*)d_in[0];
  const float* l_y   = (const float*)d_in[1];
  const float* l_pos = (const float*)d_in[2];
  const float* h_pos = (const float*)d_in[3];
  const float* W1    = (const float*)d_in[4];
  const float* b1    = (const float*)d_in[5];
  const float* W2    = (const float*)d_in[6];
  const float* b2    = (const float*)d_in[7];
  const float* W3    = (const float*)d_in[8];
  const float* b3    = (const float*)d_in[9];

  const int M = 32768, H = 512, O = 128;

  char* ws = (char*)d_ws;
  unsigned short* bufA = (unsigned short*)(ws);                  // 32 MB: X2
  unsigned short* bufB = (unsigned short*)(ws + 33554432);       // 32 MB: X1
  unsigned short* W1t  = (unsigned short*)(ws + 67108864);       // 512 KB
  unsigned short* W2t  = (unsigned short*)(ws + 67633152);       // 512 KB
  unsigned short* W3t  = (unsigned short*)(ws + 68157440);       // 128 KB
  int*    hist      = (int*)   (ws + 68288512);                  // 16 KB (4096 padded)
  int*    cellStart = (int*)   (ws + 68304896);                  // 16 KB
  int*    cursor    = (int*)   (ws + 68321280);                  // 16 KB
  float4* sorted    = (float4*)(ws + 68354048);                  // 128 KB
  float* wts = (float*)(ws + 74579968);                          // 384 KB
  int*   idx = (int*)  (ws + 74973184);                          // 384 KB

  // weight transposes (bf16 [N][K] for MFMA B-operand)
  k_transpose_cast<<<dim3(H/32, H/32), 256, 0, stream>>>(W1, W1t, H, H);
  k_transpose_cast<<<dim3(H/32, H/32), 256, 0, stream>>>(W2, W2t, H, H);
  k_transpose_cast<<<dim3(O/32, H/32), 256, 0, stream>>>(W3, W3t, H, O);

  // MLP (GEMM1 reads f32 emb directly, cast fused into staging)
  k_gemm<true,  true,  true ><<<dim3(M/128, H/128), 256, 0, stream>>>(emb,  W1t, b1, bufB, H, H);
  k_gemm<false, true,  true ><<<dim3(M/128, H/128), 256, 0, stream>>>(bufB, W2t, b2, bufA, H, H);
  k_gemm<false, false, false><<<dim3(M/128, O/128), 256, 0, stream>>>(bufA, W3t, b3, d_out, H, O);

  // KNN interpolate via uniform grid (+= into out)
  k_zero<<<dim3(1), 64, 0, stream>>>(hist);
  k_hist<<<dim3(NL/256), 256, 0, stream>>>(l_pos, hist);
  k_scan<<<dim3(1), 1024, 0, stream>>>(hist, cellStart, cursor);
  k_scatter<<<dim3(NL/256), 256, 0, stream>>>(l_pos, cursor, sorted);
  k_knn_grid<<<dim3(M*16/256), 256, 0, stream>>>(h_pos, cellStart, sorted, wts, idx);
  k_knn_gather<<<dim3(M*32/256), 256, 0, stream>>>(wts, idx, l_y, (float*)d_out);
}